// Round 1
// baseline (1484.309 us; speedup 1.0000x reference)
//
#include <hip/hip_runtime.h>
#include <hip/hip_bf16.h>
#include <math.h>

#define N_NODES 50000
#define N_EDGES 1600000
#define TE 64

__device__ __forceinline__ unsigned f32_to_ord(float f) {
    unsigned u = __float_as_uint(f);
    return (u & 0x80000000u) ? ~u : (u | 0x80000000u);
}
__device__ __forceinline__ float ord_to_f32(unsigned e) {
    unsigned u = (e & 0x80000000u) ? (e & 0x7fffffffu) : ~e;
    return __uint_as_float(u);
}

// h = concat(x, cos(t*omega+phase)) @ W ; also s_src[n,h], s_dst[n,h]
template<int IN_DIM>
__global__ __launch_bounds__(512) void transform_kernel(
    const float* __restrict__ xin, const float* __restrict__ tim,
    const float* __restrict__ omega, const float* __restrict__ phase,
    const float* __restrict__ W, const float* __restrict__ asrc,
    const float* __restrict__ adst,
    float* __restrict__ hfeat, float* __restrict__ s_src, float* __restrict__ s_dst)
{
    constexpr int K = IN_DIM + TE;
    constexpr int NPB = 8;              // nodes per block (512 threads / 64 cols)
    __shared__ float a[NPB][K];
    const int tid = threadIdx.x;
    const int base = blockIdx.x * NPB;

    for (int i = tid; i < NPB * K; i += 512) {
        int nl = i / K, k = i - nl * K;
        int n = base + nl;
        if (n < N_NODES) {
            a[nl][k] = (k < IN_DIM) ? xin[(size_t)n * IN_DIM + k]
                                    : cosf(tim[n] * omega[k - IN_DIM] + phase[k - IN_DIM]);
        }
    }
    __syncthreads();

    const int nl = tid >> 6, col = tid & 63;
    const int n = base + nl;
    if (n >= N_NODES) return;

    float acc = 0.f;
    #pragma unroll 4
    for (int k = 0; k < K; ++k) acc += a[nl][k] * W[k * 64 + col];
    hfeat[(size_t)n * 64 + col] = acc;

    float vs = acc * asrc[col];
    float vd = acc * adst[col];
    #pragma unroll
    for (int off = 8; off; off >>= 1) {
        vs += __shfl_xor(vs, off, 64);
        vd += __shfl_xor(vd, off, 64);
    }
    if ((col & 15) == 0) {
        s_src[n * 4 + (col >> 4)] = vs;
        s_dst[n * 4 + (col >> 4)] = vd;
    }
}

__global__ __launch_bounds__(256) void init_kernel(
    float* __restrict__ agg, float* __restrict__ den, unsigned* __restrict__ m)
{
    int i = blockIdx.x * 256 + threadIdx.x;
    if (i < N_NODES * 64) agg[i] = 0.f;
    if (i < N_NODES * 4) { den[i] = 0.f; m[i] = 0x007FFFFFu; /* ord(-inf) */ }
}

__global__ __launch_bounds__(256) void edge_max_kernel(
    const int* __restrict__ src, const int* __restrict__ dst,
    const float* __restrict__ s_src, const float* __restrict__ s_dst,
    unsigned* __restrict__ m)
{
    int e = blockIdx.x * 256 + threadIdx.x;
    if (e >= N_EDGES) return;
    int s = src[e], d = dst[e];
    float4 ss = *(const float4*)(s_src + (size_t)s * 4);
    float4 sd = *(const float4*)(s_dst + (size_t)d * 4);
    float sc[4] = {ss.x + sd.x, ss.y + sd.y, ss.z + sd.z, ss.w + sd.w};
    #pragma unroll
    for (int h = 0; h < 4; ++h) {
        float v = sc[h] >= 0.f ? sc[h] : 0.2f * sc[h];
        atomicMax(m + (size_t)d * 4 + h, f32_to_ord(v));
    }
}

// 16 lanes per edge: num = exp(e - m[dst]) * ew ; den += num ; agg[dst] += num*h[src]
__global__ __launch_bounds__(256) void edge_acc_kernel(
    const int* __restrict__ src, const int* __restrict__ dst,
    const float* __restrict__ ew,
    const float* __restrict__ s_src, const float* __restrict__ s_dst,
    const unsigned* __restrict__ m,
    const float* __restrict__ hfeat,
    float* __restrict__ agg, float* __restrict__ den)
{
    const int tid = threadIdx.x;
    const int e = blockIdx.x * 16 + (tid >> 4);
    if (e >= N_EDGES) return;
    const int lane = tid & 15;
    const int s = src[e], d = dst[e];
    const float w = ew[e];

    float num = 0.f;
    if (lane < 4) {
        float sc = s_src[(size_t)s * 4 + lane] + s_dst[(size_t)d * 4 + lane];
        sc = sc >= 0.f ? sc : 0.2f * sc;
        float mx = ord_to_f32(m[(size_t)d * 4 + lane]);
        num = expf(sc - mx) * w;
        atomicAdd(den + (size_t)d * 4 + lane, num);
    }
    const int gb = (tid & 63) & 48;   // group base lane within wave
    #pragma unroll
    for (int h = 0; h < 4; ++h) {
        float nh = __shfl(num, gb + h, 64);
        float hv = hfeat[(size_t)s * 64 + h * 16 + lane];
        atomicAdd(agg + (size_t)d * 64 + h * 16 + lane, nh * hv);
    }
}

__global__ __launch_bounds__(256) void finalize_l0_kernel(
    const float* __restrict__ agg, const float* __restrict__ den, float* __restrict__ x1)
{
    int i = blockIdx.x * 256 + threadIdx.x;
    if (i >= N_NODES * 64) return;
    int n = i >> 6, j = i & 63;
    float v = agg[i] / (den[n * 4 + (j >> 4)] + 1e-16f);
    x1[i] = v > 0.f ? v : expm1f(v);   // elu
}

__global__ __launch_bounds__(256) void head_kernel(
    const float* __restrict__ agg, const float* __restrict__ den,
    const float* __restrict__ whead, const float* __restrict__ bhead,
    float* __restrict__ out)
{
    int n = blockIdx.x * 4 + (threadIdx.x >> 6);
    if (n >= N_NODES) return;
    int j = threadIdx.x & 63;
    float v = agg[(size_t)n * 64 + j] / (den[n * 4 + (j >> 4)] + 1e-16f);
    v *= whead[j];
    #pragma unroll
    for (int off = 32; off; off >>= 1) v += __shfl_xor(v, off, 64);
    if (j == 0) out[n] = v + bhead[0];
}

extern "C" void kernel_launch(void* const* d_in, const int* in_sizes, int n_in,
                              void* d_out, int out_size, void* d_ws, size_t ws_size,
                              hipStream_t stream) {
    const float* x      = (const float*)d_in[0];
    const int*   eidx   = (const int*)d_in[1];
    const float* ew     = (const float*)d_in[2];
    const float* tim    = (const float*)d_in[3];
    const float* omega0 = (const float*)d_in[4];
    const float* phase0 = (const float*)d_in[5];
    const float* W0     = (const float*)d_in[6];
    const float* asrc0  = (const float*)d_in[7];
    const float* adst0  = (const float*)d_in[8];
    const float* omega1 = (const float*)d_in[9];
    const float* phase1 = (const float*)d_in[10];
    const float* W1     = (const float*)d_in[11];
    const float* asrc1  = (const float*)d_in[12];
    const float* adst1  = (const float*)d_in[13];
    const float* Whead  = (const float*)d_in[14];
    const float* bhead  = (const float*)d_in[15];
    float* out = (float*)d_out;

    const int* src = eidx;
    const int* dst = eidx + N_EDGES;

    float* ws = (float*)d_ws;
    float* hfeat = ws;                         // N*64
    float* agg   = hfeat + (size_t)N_NODES * 64;  // N*64
    float* x1    = agg   + (size_t)N_NODES * 64;  // N*64
    float* s_src = x1    + (size_t)N_NODES * 64;  // N*4
    float* s_dst = s_src + (size_t)N_NODES * 4;   // N*4
    unsigned* m  = (unsigned*)(s_dst + (size_t)N_NODES * 4); // N*4
    float* den   = (float*)(m + (size_t)N_NODES * 4);        // N*4

    const int tf_grid   = (N_NODES + 7) / 8;
    const int init_grid = (N_NODES * 64 + 255) / 256;
    const int emax_grid = (N_EDGES + 255) / 256;
    const int eacc_grid = (N_EDGES + 15) / 16;
    const int node_grid = (N_NODES + 3) / 4;

    // ---- layer 0 ----
    transform_kernel<128><<<tf_grid, 512, 0, stream>>>(
        x, tim, omega0, phase0, W0, asrc0, adst0, hfeat, s_src, s_dst);
    init_kernel<<<init_grid, 256, 0, stream>>>(agg, den, m);
    edge_max_kernel<<<emax_grid, 256, 0, stream>>>(src, dst, s_src, s_dst, m);
    edge_acc_kernel<<<eacc_grid, 256, 0, stream>>>(
        src, dst, ew, s_src, s_dst, m, hfeat, agg, den);
    finalize_l0_kernel<<<init_grid, 256, 0, stream>>>(agg, den, x1);

    // ---- layer 1 ----
    transform_kernel<64><<<tf_grid, 512, 0, stream>>>(
        x1, tim, omega1, phase1, W1, asrc1, adst1, hfeat, s_src, s_dst);
    init_kernel<<<init_grid, 256, 0, stream>>>(agg, den, m);
    edge_max_kernel<<<emax_grid, 256, 0, stream>>>(src, dst, s_src, s_dst, m);
    edge_acc_kernel<<<eacc_grid, 256, 0, stream>>>(
        src, dst, ew, s_src, s_dst, m, hfeat, agg, den);

    // ---- head ----
    head_kernel<<<node_grid, 256, 0, stream>>>(agg, den, Whead, bhead, out);
}

// Round 2
// 696.539 us; speedup vs baseline: 2.1310x; 2.1310x over previous
//
#include <hip/hip_runtime.h>
#include <hip/hip_bf16.h>
#include <math.h>

#define N_NODES 50000
#define N_EDGES 1600000
#define TE 64
#define NB_SCAN 196   // ceil(50000/256)

// ---------------- node transform ----------------
// h = concat(x, cos(t*omega+phase)) @ W ; also s_src[n,h], s_dst[n,h]
template<int IN_DIM>
__global__ __launch_bounds__(512) void transform_kernel(
    const float* __restrict__ xin, const float* __restrict__ tim,
    const float* __restrict__ omega, const float* __restrict__ phase,
    const float* __restrict__ W, const float* __restrict__ asrc,
    const float* __restrict__ adst,
    float* __restrict__ hfeat, float* __restrict__ s_src, float* __restrict__ s_dst)
{
    constexpr int K = IN_DIM + TE;
    constexpr int NPB = 8;              // nodes per block (512 threads / 64 cols)
    __shared__ float a[NPB][K];
    const int tid = threadIdx.x;
    const int base = blockIdx.x * NPB;

    for (int i = tid; i < NPB * K; i += 512) {
        int nl = i / K, k = i - nl * K;
        int n = base + nl;
        if (n < N_NODES) {
            a[nl][k] = (k < IN_DIM) ? xin[(size_t)n * IN_DIM + k]
                                    : cosf(tim[n] * omega[k - IN_DIM] + phase[k - IN_DIM]);
        }
    }
    __syncthreads();

    const int nl = tid >> 6, col = tid & 63;
    const int n = base + nl;
    if (n >= N_NODES) return;

    float acc = 0.f;
    #pragma unroll 4
    for (int k = 0; k < K; ++k) acc += a[nl][k] * W[k * 64 + col];
    hfeat[(size_t)n * 64 + col] = acc;

    float vs = acc * asrc[col];
    float vd = acc * adst[col];
    #pragma unroll
    for (int off = 8; off; off >>= 1) {
        vs += __shfl_xor(vs, off, 64);
        vd += __shfl_xor(vd, off, 64);
    }
    if ((col & 15) == 0) {
        s_src[n * 4 + (col >> 4)] = vs;
        s_dst[n * 4 + (col >> 4)] = vd;
    }
}

// ---------------- CSR build ----------------
__global__ __launch_bounds__(256) void hist_kernel(
    const int* __restrict__ dst, int* __restrict__ deg)
{
    int e = blockIdx.x * 256 + threadIdx.x;
    if (e < N_EDGES) atomicAdd(deg + dst[e], 1);
}

__global__ __launch_bounds__(256) void scanA_kernel(
    const int* __restrict__ deg, int* __restrict__ bsum)
{
    __shared__ int sd[4];
    int i = blockIdx.x * 256 + threadIdx.x;
    int v = (i < N_NODES) ? deg[i] : 0;
    #pragma unroll
    for (int off = 32; off; off >>= 1) v += __shfl_xor(v, off, 64);
    if ((threadIdx.x & 63) == 0) sd[threadIdx.x >> 6] = v;
    __syncthreads();
    if (threadIdx.x == 0) bsum[blockIdx.x] = sd[0] + sd[1] + sd[2] + sd[3];
}

__global__ __launch_bounds__(256) void scanB_kernel(int* __restrict__ bsum)
{
    __shared__ int s[256];
    int t = threadIdx.x;
    int v = (t < NB_SCAN) ? bsum[t] : 0;
    s[t] = v;
    __syncthreads();
    #pragma unroll
    for (int off = 1; off < 256; off <<= 1) {
        int u = (t >= off) ? s[t - off] : 0;
        __syncthreads();
        s[t] += u;
        __syncthreads();
    }
    if (t < NB_SCAN) bsum[t] = s[t] - v;   // exclusive
}

__global__ __launch_bounds__(256) void scanC_kernel(
    const int* __restrict__ deg, const int* __restrict__ bsum,
    int* __restrict__ rowptr, int* __restrict__ cursor)
{
    __shared__ int s[256];
    int t = threadIdx.x;
    int i = blockIdx.x * 256 + t;
    int v = (i < N_NODES) ? deg[i] : 0;
    s[t] = v;
    __syncthreads();
    #pragma unroll
    for (int off = 1; off < 256; off <<= 1) {
        int u = (t >= off) ? s[t - off] : 0;
        __syncthreads();
        s[t] += u;
        __syncthreads();
    }
    int excl = s[t] - v + bsum[blockIdx.x];
    if (i < N_NODES) { rowptr[i] = excl; cursor[i] = excl; }
}

__global__ __launch_bounds__(256) void scatter_kernel(
    const int* __restrict__ src, const int* __restrict__ dst,
    const float* __restrict__ ew,
    int* __restrict__ cursor, int* __restrict__ esrc, float* __restrict__ eww)
{
    int e = blockIdx.x * 256 + threadIdx.x;
    if (e >= N_EDGES) return;
    int pos = atomicAdd(cursor + dst[e], 1);
    esrc[pos] = src[e];
    eww[pos] = ew[e];
}

// ---------------- fused per-dst aggregation (online softmax) ----------------
// one wave per node; lane = feature col (4 heads x 16 dims)
template<int FINAL>
__global__ __launch_bounds__(256) void aggregate_kernel(
    const int* __restrict__ rowptr, const int* __restrict__ deg,
    const int* __restrict__ esrc, const float* __restrict__ eww,
    const float* __restrict__ s_src, const float* __restrict__ s_dst,
    const float* __restrict__ hfeat,
    const float* __restrict__ whead, const float* __restrict__ bhead,
    float* __restrict__ outp)
{
    const int n = blockIdx.x * 4 + (threadIdx.x >> 6);
    if (n >= N_NODES) return;
    const int lane = threadIdx.x & 63;
    const int hg = lane >> 4;
    const float sdst = s_dst[n * 4 + hg];
    const int beg = rowptr[n];
    const int cnt = deg[n];

    float m = -3.4e38f, den = 0.f, acc = 0.f;

    int s = (cnt > 0) ? esrc[beg] : 0;
    float w = (cnt > 0) ? eww[beg] : 0.f;
    for (int i = 0; i < cnt; ++i) {
        const int s_next = (i + 1 < cnt) ? esrc[beg + i + 1] : 0;
        const float w_next = (i + 1 < cnt) ? eww[beg + i + 1] : 0.f;
        float sc = s_src[(size_t)s * 4 + hg] + sdst;
        sc = sc >= 0.f ? sc : 0.2f * sc;
        const float hv = hfeat[(size_t)s * 64 + lane];
        if (sc > m) {
            const float r = expf(m - sc);     // first iter: exp(-inf)=0
            den = den * r + w;
            acc = acc * r + w * hv;
            m = sc;
        } else {
            const float p = expf(sc - m) * w;
            den += p;
            acc += p * hv;
        }
        s = s_next; w = w_next;
    }

    const float inv = 1.f / (den + 1e-16f);
    if (!FINAL) {
        float v = acc * inv;
        outp[(size_t)n * 64 + lane] = v > 0.f ? v : expm1f(v);   // ELU
    } else {
        float v = acc * inv * whead[lane];
        #pragma unroll
        for (int off = 32; off; off >>= 1) v += __shfl_xor(v, off, 64);
        if (lane == 0) outp[n] = v + bhead[0];
    }
}

extern "C" void kernel_launch(void* const* d_in, const int* in_sizes, int n_in,
                              void* d_out, int out_size, void* d_ws, size_t ws_size,
                              hipStream_t stream) {
    const float* x      = (const float*)d_in[0];
    const int*   eidx   = (const int*)d_in[1];
    const float* ew     = (const float*)d_in[2];
    const float* tim    = (const float*)d_in[3];
    const float* omega0 = (const float*)d_in[4];
    const float* phase0 = (const float*)d_in[5];
    const float* W0     = (const float*)d_in[6];
    const float* asrc0  = (const float*)d_in[7];
    const float* adst0  = (const float*)d_in[8];
    const float* omega1 = (const float*)d_in[9];
    const float* phase1 = (const float*)d_in[10];
    const float* W1     = (const float*)d_in[11];
    const float* asrc1  = (const float*)d_in[12];
    const float* adst1  = (const float*)d_in[13];
    const float* Whead  = (const float*)d_in[14];
    const float* bhead  = (const float*)d_in[15];
    float* out = (float*)d_out;

    const int* src = eidx;
    const int* dst = eidx + N_EDGES;

    float* ws = (float*)d_ws;
    float* hfeat = ws;                               // N*64
    float* x1    = hfeat + (size_t)N_NODES * 64;     // N*64
    float* s_src = x1    + (size_t)N_NODES * 64;     // N*4
    float* s_dst = s_src + (size_t)N_NODES * 4;      // N*4
    float* eww   = s_dst + (size_t)N_NODES * 4;      // E
    int* esrc    = (int*)(eww + (size_t)N_EDGES);    // E
    int* deg     = esrc + (size_t)N_EDGES;           // N
    int* rowptr  = deg + N_NODES;                    // N
    int* cursor  = rowptr + N_NODES;                 // N
    int* bsum    = cursor + N_NODES;                 // 256

    const int tf_grid   = (N_NODES + 7) / 8;
    const int edge_grid = (N_EDGES + 255) / 256;
    const int agg_grid  = (N_NODES + 3) / 4;

    // ---- CSR build (edge structure shared by both layers) ----
    hipMemsetAsync(deg, 0, N_NODES * sizeof(int), stream);
    hist_kernel<<<edge_grid, 256, 0, stream>>>(dst, deg);
    scanA_kernel<<<NB_SCAN, 256, 0, stream>>>(deg, bsum);
    scanB_kernel<<<1, 256, 0, stream>>>(bsum);
    scanC_kernel<<<NB_SCAN, 256, 0, stream>>>(deg, bsum, rowptr, cursor);
    scatter_kernel<<<edge_grid, 256, 0, stream>>>(src, dst, ew, cursor, esrc, eww);

    // ---- layer 0 ----
    transform_kernel<128><<<tf_grid, 512, 0, stream>>>(
        x, tim, omega0, phase0, W0, asrc0, adst0, hfeat, s_src, s_dst);
    aggregate_kernel<0><<<agg_grid, 256, 0, stream>>>(
        rowptr, deg, esrc, eww, s_src, s_dst, hfeat, Whead, bhead, x1);

    // ---- layer 1 (+ fused linear head) ----
    transform_kernel<64><<<tf_grid, 512, 0, stream>>>(
        x1, tim, omega1, phase1, W1, asrc1, adst1, hfeat, s_src, s_dst);
    aggregate_kernel<1><<<agg_grid, 256, 0, stream>>>(
        rowptr, deg, esrc, eww, s_src, s_dst, hfeat, Whead, bhead, out);
}

// Round 3
// 456.298 us; speedup vs baseline: 3.2529x; 1.5265x over previous
//
#include <hip/hip_runtime.h>
#include <hip/hip_bf16.h>
#include <math.h>

#define N_NODES 50000
#define N_EDGES 1600000
#define TE 64
#define NB_SCAN 196   // ceil(50000/256)
#define LOG2E 1.44269504088896340736f

// ---------------- node transform ----------------
// h = concat(x, cos(t*omega+phase)) @ W ; also s_src[n,h], s_dst[n,h] (pre-scaled by log2e)
template<int IN_DIM>
__global__ __launch_bounds__(512) void transform_kernel(
    const float* __restrict__ xin, const float* __restrict__ tim,
    const float* __restrict__ omega, const float* __restrict__ phase,
    const float* __restrict__ W, const float* __restrict__ asrc,
    const float* __restrict__ adst,
    float* __restrict__ hfeat, float* __restrict__ s_src, float* __restrict__ s_dst)
{
    constexpr int K = IN_DIM + TE;
    constexpr int NPB = 8;              // nodes per block (512 threads / 64 cols)
    __shared__ float a[NPB][K];
    const int tid = threadIdx.x;
    const int base = blockIdx.x * NPB;

    for (int i = tid; i < NPB * K; i += 512) {
        int nl = i / K, k = i - nl * K;
        int n = base + nl;
        if (n < N_NODES) {
            a[nl][k] = (k < IN_DIM) ? xin[(size_t)n * IN_DIM + k]
                                    : cosf(tim[n] * omega[k - IN_DIM] + phase[k - IN_DIM]);
        }
    }
    __syncthreads();

    const int nl = tid >> 6, col = tid & 63;
    const int n = base + nl;
    if (n >= N_NODES) return;

    float acc = 0.f;
    #pragma unroll 4
    for (int k = 0; k < K; ++k) acc += a[nl][k] * W[k * 64 + col];
    hfeat[(size_t)n * 64 + col] = acc;

    float vs = acc * asrc[col];
    float vd = acc * adst[col];
    #pragma unroll
    for (int off = 8; off; off >>= 1) {
        vs += __shfl_xor(vs, off, 64);
        vd += __shfl_xor(vd, off, 64);
    }
    if ((col & 15) == 0) {
        s_src[n * 4 + (col >> 4)] = vs * LOG2E;   // exp2 domain
        s_dst[n * 4 + (col >> 4)] = vd * LOG2E;
    }
}

// ---------------- CSR build ----------------
__global__ __launch_bounds__(256) void hist_kernel(
    const int* __restrict__ dst, int* __restrict__ deg)
{
    int e = blockIdx.x * 256 + threadIdx.x;
    if (e < N_EDGES) atomicAdd(deg + dst[e], 1);
}

__global__ __launch_bounds__(256) void scanA_kernel(
    const int* __restrict__ deg, int* __restrict__ bsum)
{
    __shared__ int sd[4];
    int i = blockIdx.x * 256 + threadIdx.x;
    int v = (i < N_NODES) ? deg[i] : 0;
    #pragma unroll
    for (int off = 32; off; off >>= 1) v += __shfl_xor(v, off, 64);
    if ((threadIdx.x & 63) == 0) sd[threadIdx.x >> 6] = v;
    __syncthreads();
    if (threadIdx.x == 0) bsum[blockIdx.x] = sd[0] + sd[1] + sd[2] + sd[3];
}

__global__ __launch_bounds__(256) void scanB_kernel(int* __restrict__ bsum)
{
    __shared__ int s[256];
    int t = threadIdx.x;
    int v = (t < NB_SCAN) ? bsum[t] : 0;
    s[t] = v;
    __syncthreads();
    #pragma unroll
    for (int off = 1; off < 256; off <<= 1) {
        int u = (t >= off) ? s[t - off] : 0;
        __syncthreads();
        s[t] += u;
        __syncthreads();
    }
    if (t < NB_SCAN) bsum[t] = s[t] - v;   // exclusive
}

__global__ __launch_bounds__(256) void scanC_kernel(
    const int* __restrict__ deg, const int* __restrict__ bsum,
    int* __restrict__ rowptr, int* __restrict__ cursor)
{
    __shared__ int s[256];
    int t = threadIdx.x;
    int i = blockIdx.x * 256 + t;
    int v = (i < N_NODES) ? deg[i] : 0;
    s[t] = v;
    __syncthreads();
    #pragma unroll
    for (int off = 1; off < 256; off <<= 1) {
        int u = (t >= off) ? s[t - off] : 0;
        __syncthreads();
        s[t] += u;
        __syncthreads();
    }
    int excl = s[t] - v + bsum[blockIdx.x];
    if (i < N_NODES) { rowptr[i] = excl; cursor[i] = excl; }
}

__global__ __launch_bounds__(256) void scatter_kernel(
    const int* __restrict__ src, const int* __restrict__ dst,
    const float* __restrict__ ew,
    int* __restrict__ cursor, int2* __restrict__ epair)
{
    int e = blockIdx.x * 256 + threadIdx.x;
    if (e >= N_EDGES) return;
    int pos = atomicAdd(cursor + dst[e], 1);
    epair[pos] = make_int2(src[e], __float_as_int(ew[e]));
}

// ---------------- fused per-dst aggregation ----------------
// one wave per node; 4 subgroups x 16 lanes, 4 edges in flight;
// each lane holds float4 of features (16 lanes x 4 = 64 features).
// no max-subtraction (scores O(1), softmax is shift-invariant).
template<int FINAL>
__global__ __launch_bounds__(256) void aggregate_kernel(
    const int* __restrict__ rowptr, const int* __restrict__ deg,
    const int2* __restrict__ epair,
    const float* __restrict__ s_src, const float* __restrict__ s_dst,
    const float* __restrict__ hfeat,
    const float* __restrict__ whead, const float* __restrict__ bhead,
    float* __restrict__ outp)
{
    const int n = blockIdx.x * 4 + (threadIdx.x >> 6);
    if (n >= N_NODES) return;
    const int lane = threadIdx.x & 63;
    const int g = lane >> 4;          // subgroup (edge slot)
    const int sl = lane & 15;         // sub-lane: features sl*4..sl*4+3
    const int hh = sl >> 2;           // head of my features
    const float sdst = s_dst[n * 4 + hh];
    const int beg = rowptr[n];
    const int cnt = deg[n];

    float den = 0.f;
    float4 acc = make_float4(0.f, 0.f, 0.f, 0.f);

    int i = g;
    int2 ep = (i < cnt) ? epair[beg + i] : make_int2(0, 0);
    while (i < cnt) {
        const int inext = i + 4;
        int2 epn = (inext < cnt) ? epair[beg + inext] : make_int2(0, 0);
        const int s = ep.x;
        const float w = __int_as_float(ep.y);
        float sc = s_src[(size_t)s * 4 + hh] + sdst;
        sc = fmaxf(sc, 0.2f * sc);                       // leaky relu (log2 domain)
        const float p = __builtin_amdgcn_exp2f(sc) * w;
        const float4 hv = *(const float4*)(hfeat + (size_t)s * 64 + sl * 4);
        den += p;
        acc.x = fmaf(p, hv.x, acc.x);
        acc.y = fmaf(p, hv.y, acc.y);
        acc.z = fmaf(p, hv.z, acc.z);
        acc.w = fmaf(p, hv.w, acc.w);
        ep = epn; i = inext;
    }

    // merge 4 subgroups (lanes differing in bits 4,5)
    #pragma unroll
    for (int off = 16; off <= 32; off <<= 1) {
        den   += __shfl_xor(den, off, 64);
        acc.x += __shfl_xor(acc.x, off, 64);
        acc.y += __shfl_xor(acc.y, off, 64);
        acc.z += __shfl_xor(acc.z, off, 64);
        acc.w += __shfl_xor(acc.w, off, 64);
    }

    const float inv = 1.f / (den + 1e-16f);
    if (!FINAL) {
        if (g == 0) {
            float4 v;
            v.x = acc.x * inv; v.x = v.x > 0.f ? v.x : expm1f(v.x);
            v.y = acc.y * inv; v.y = v.y > 0.f ? v.y : expm1f(v.y);
            v.z = acc.z * inv; v.z = v.z > 0.f ? v.z : expm1f(v.z);
            v.w = acc.w * inv; v.w = v.w > 0.f ? v.w : expm1f(v.w);
            *(float4*)(outp + (size_t)n * 64 + sl * 4) = v;
        }
    } else {
        const float4 wh = *(const float4*)(whead + sl * 4);
        float v = (acc.x * wh.x + acc.y * wh.y + acc.z * wh.z + acc.w * wh.w) * inv;
        #pragma unroll
        for (int off = 1; off <= 8; off <<= 1) v += __shfl_xor(v, off, 64);
        if (lane == 0) outp[n] = v + bhead[0];
    }
}

extern "C" void kernel_launch(void* const* d_in, const int* in_sizes, int n_in,
                              void* d_out, int out_size, void* d_ws, size_t ws_size,
                              hipStream_t stream) {
    const float* x      = (const float*)d_in[0];
    const int*   eidx   = (const int*)d_in[1];
    const float* ew     = (const float*)d_in[2];
    const float* tim    = (const float*)d_in[3];
    const float* omega0 = (const float*)d_in[4];
    const float* phase0 = (const float*)d_in[5];
    const float* W0     = (const float*)d_in[6];
    const float* asrc0  = (const float*)d_in[7];
    const float* adst0  = (const float*)d_in[8];
    const float* omega1 = (const float*)d_in[9];
    const float* phase1 = (const float*)d_in[10];
    const float* W1     = (const float*)d_in[11];
    const float* asrc1  = (const float*)d_in[12];
    const float* adst1  = (const float*)d_in[13];
    const float* Whead  = (const float*)d_in[14];
    const float* bhead  = (const float*)d_in[15];
    float* out = (float*)d_out;

    const int* src = eidx;
    const int* dst = eidx + N_EDGES;

    float* ws = (float*)d_ws;
    float* hfeat = ws;                               // N*64
    float* x1    = hfeat + (size_t)N_NODES * 64;     // N*64
    float* s_src = x1    + (size_t)N_NODES * 64;     // N*4
    float* s_dst = s_src + (size_t)N_NODES * 4;      // N*4
    int2* epair  = (int2*)(s_dst + (size_t)N_NODES * 4);   // E (8B each)
    int* deg     = (int*)(epair + (size_t)N_EDGES);  // N
    int* rowptr  = deg + N_NODES;                    // N
    int* cursor  = rowptr + N_NODES;                 // N
    int* bsum    = cursor + N_NODES;                 // 256

    const int tf_grid   = (N_NODES + 7) / 8;
    const int edge_grid = (N_EDGES + 255) / 256;
    const int agg_grid  = (N_NODES + 3) / 4;

    // ---- CSR build (edge structure shared by both layers) ----
    hipMemsetAsync(deg, 0, N_NODES * sizeof(int), stream);
    hist_kernel<<<edge_grid, 256, 0, stream>>>(dst, deg);
    scanA_kernel<<<NB_SCAN, 256, 0, stream>>>(deg, bsum);
    scanB_kernel<<<1, 256, 0, stream>>>(bsum);
    scanC_kernel<<<NB_SCAN, 256, 0, stream>>>(deg, bsum, rowptr, cursor);
    scatter_kernel<<<edge_grid, 256, 0, stream>>>(src, dst, ew, cursor, epair);

    // ---- layer 0 ----
    transform_kernel<128><<<tf_grid, 512, 0, stream>>>(
        x, tim, omega0, phase0, W0, asrc0, adst0, hfeat, s_src, s_dst);
    aggregate_kernel<0><<<agg_grid, 256, 0, stream>>>(
        rowptr, deg, epair, s_src, s_dst, hfeat, Whead, bhead, x1);

    // ---- layer 1 (+ fused linear head) ----
    transform_kernel<64><<<tf_grid, 512, 0, stream>>>(
        x1, tim, omega1, phase1, W1, asrc1, adst1, hfeat, s_src, s_dst);
    aggregate_kernel<1><<<agg_grid, 256, 0, stream>>>(
        rowptr, deg, epair, s_src, s_dst, hfeat, Whead, bhead, out);
}

// Round 4
// 381.596 us; speedup vs baseline: 3.8897x; 1.1958x over previous
//
#include <hip/hip_runtime.h>
#include <hip/hip_bf16.h>
#include <math.h>

#define N_NODES 50000
#define N_EDGES 1600000
#define TE 64
#define NB_SCAN 196   // ceil(50000/256)
#define LOG2E 1.44269504088896340736f
#define SC_CHUNK 2048
#define NSEG 8        // dst-range segments (one per XCD)
#define SEG_W (N_NODES / NSEG)   // 6250

// ---------------- node transform ----------------
// h = concat(x, cos(t*omega+phase)) @ W ; also s_src[n,h], s_dst[n,h] (pre-scaled by log2e)
template<int IN_DIM>
__global__ __launch_bounds__(512) void transform_kernel(
    const float* __restrict__ xin, const float* __restrict__ tim,
    const float* __restrict__ omega, const float* __restrict__ phase,
    const float* __restrict__ W, const float* __restrict__ asrc,
    const float* __restrict__ adst,
    float* __restrict__ hfeat, float* __restrict__ s_src, float* __restrict__ s_dst)
{
    constexpr int K = IN_DIM + TE;
    constexpr int NPB = 8;              // nodes per block (512 threads / 64 cols)
    __shared__ float a[NPB][K];
    const int tid = threadIdx.x;
    const int base = blockIdx.x * NPB;

    for (int i = tid; i < NPB * K; i += 512) {
        int nl = i / K, k = i - nl * K;
        int n = base + nl;
        if (n < N_NODES) {
            a[nl][k] = (k < IN_DIM) ? xin[(size_t)n * IN_DIM + k]
                                    : cosf(tim[n] * omega[k - IN_DIM] + phase[k - IN_DIM]);
        }
    }
    __syncthreads();

    const int nl = tid >> 6, col = tid & 63;
    const int n = base + nl;
    if (n >= N_NODES) return;

    float acc = 0.f;
    #pragma unroll 4
    for (int k = 0; k < K; ++k) acc += a[nl][k] * W[k * 64 + col];
    hfeat[(size_t)n * 64 + col] = acc;

    float vs = acc * asrc[col];
    float vd = acc * adst[col];
    #pragma unroll
    for (int off = 8; off; off >>= 1) {
        vs += __shfl_xor(vs, off, 64);
        vd += __shfl_xor(vd, off, 64);
    }
    if ((col & 15) == 0) {
        s_src[n * 4 + (col >> 4)] = vs * LOG2E;   // exp2 domain
        s_dst[n * 4 + (col >> 4)] = vd * LOG2E;
    }
}

// ---------------- CSR build ----------------
// deg count + per-edge rank (order within its dst segment)
__global__ __launch_bounds__(256) void hist_kernel(
    const int* __restrict__ dst, int* __restrict__ deg, int* __restrict__ rank)
{
    int e = blockIdx.x * 256 + threadIdx.x;
    if (e < N_EDGES) rank[e] = atomicAdd(deg + dst[e], 1);
}

__global__ __launch_bounds__(256) void scanA_kernel(
    const int* __restrict__ deg, int* __restrict__ bsum)
{
    __shared__ int sd[4];
    int i = blockIdx.x * 256 + threadIdx.x;
    int v = (i < N_NODES) ? deg[i] : 0;
    #pragma unroll
    for (int off = 32; off; off >>= 1) v += __shfl_xor(v, off, 64);
    if ((threadIdx.x & 63) == 0) sd[threadIdx.x >> 6] = v;
    __syncthreads();
    if (threadIdx.x == 0) bsum[blockIdx.x] = sd[0] + sd[1] + sd[2] + sd[3];
}

__global__ __launch_bounds__(256) void scanB_kernel(int* __restrict__ bsum)
{
    __shared__ int s[256];
    int t = threadIdx.x;
    int v = (t < NB_SCAN) ? bsum[t] : 0;
    s[t] = v;
    __syncthreads();
    #pragma unroll
    for (int off = 1; off < 256; off <<= 1) {
        int u = (t >= off) ? s[t - off] : 0;
        __syncthreads();
        s[t] += u;
        __syncthreads();
    }
    if (t < NB_SCAN) bsum[t] = s[t] - v;   // exclusive
}

__global__ __launch_bounds__(256) void scanC_kernel(
    const int* __restrict__ deg, const int* __restrict__ bsum,
    int* __restrict__ rowptr)
{
    __shared__ int s[256];
    int t = threadIdx.x;
    int i = blockIdx.x * 256 + t;
    int v = (i < N_NODES) ? deg[i] : 0;
    s[t] = v;
    __syncthreads();
    #pragma unroll
    for (int off = 1; off < 256; off <<= 1) {
        int u = (t >= off) ? s[t - off] : 0;
        __syncthreads();
        s[t] += u;
        __syncthreads();
    }
    int excl = s[t] - v + bsum[blockIdx.x];
    if (i < N_NODES) rowptr[i] = excl;
}

// XCD-affine scatter: block tag (blockIdx%8) owns one dst-range segment; the
// 1.6MB epair slice per segment stays resident in the owning XCD's L2, so
// random 8B writes merge into full lines before writeback. Atomic-free (rank
// precomputed in hist). Correct for ANY block->XCD mapping; %8 only buys locality.
__global__ __launch_bounds__(256) void scatter_kernel(
    const int* __restrict__ dst, const int* __restrict__ src,
    const float* __restrict__ ew, const int* __restrict__ rank,
    const int* __restrict__ rowptr, int2* __restrict__ epair)
{
    const int seg = blockIdx.x & (NSEG - 1);
    const int lo = seg * SEG_W, hi = lo + SEG_W;
    const int base = (blockIdx.x >> 3) * SC_CHUNK;
    const int end = (base + SC_CHUNK < N_EDGES) ? base + SC_CHUNK : N_EDGES;
    for (int e = base + threadIdx.x; e < end; e += 256) {
        int d = dst[e];
        if (d >= lo && d < hi) {
            epair[rowptr[d] + rank[e]] = make_int2(src[e], __float_as_int(ew[e]));
        }
    }
}

// ---------------- fused per-dst aggregation ----------------
// one wave per node; 8 subgroups x 8 lanes, 8 edges in flight;
// each lane holds 8 features (two float4): cols [sl*8, sl*8+8).
// no max-subtraction (scores O(1), softmax is shift-invariant); exp2 domain.
template<int FINAL>
__global__ __launch_bounds__(256) void aggregate_kernel(
    const int* __restrict__ rowptr, const int* __restrict__ deg,
    const int2* __restrict__ epair,
    const float* __restrict__ s_src, const float* __restrict__ s_dst,
    const float* __restrict__ hfeat,
    const float* __restrict__ whead, const float* __restrict__ bhead,
    float* __restrict__ outp)
{
    const int n = blockIdx.x * 4 + (threadIdx.x >> 6);
    if (n >= N_NODES) return;
    const int lane = threadIdx.x & 63;
    const int g = lane >> 3;          // subgroup (edge slot 0..7)
    const int sl = lane & 7;          // feature octet
    const int hh = sl >> 1;           // head of my features
    const float sdst = s_dst[n * 4 + hh];
    const int beg = rowptr[n];
    const int cnt = deg[n];

    float den = 0.f;
    float4 a0 = make_float4(0.f, 0.f, 0.f, 0.f);
    float4 a1 = make_float4(0.f, 0.f, 0.f, 0.f);

    int i = g;
    int2 ep = (i < cnt) ? epair[beg + i] : make_int2(0, 0);
    while (i < cnt) {
        const int inext = i + 8;
        int2 epn = (inext < cnt) ? epair[beg + inext] : make_int2(0, 0);
        const int s = ep.x;
        const float w = __int_as_float(ep.y);
        float sc = s_src[(size_t)s * 4 + hh] + sdst;
        sc = fmaxf(sc, 0.2f * sc);                       // leaky relu (log2 domain)
        const float p = __builtin_amdgcn_exp2f(sc) * w;
        const float4* hp = (const float4*)(hfeat + (size_t)s * 64 + sl * 8);
        const float4 h0 = hp[0];
        const float4 h1 = hp[1];
        den += p;
        a0.x = fmaf(p, h0.x, a0.x); a0.y = fmaf(p, h0.y, a0.y);
        a0.z = fmaf(p, h0.z, a0.z); a0.w = fmaf(p, h0.w, a0.w);
        a1.x = fmaf(p, h1.x, a1.x); a1.y = fmaf(p, h1.y, a1.y);
        a1.z = fmaf(p, h1.z, a1.z); a1.w = fmaf(p, h1.w, a1.w);
        ep = epn; i = inext;
    }

    // merge 8 subgroups (lane bits 3,4,5)
    #pragma unroll
    for (int off = 8; off <= 32; off <<= 1) {
        den  += __shfl_xor(den, off, 64);
        a0.x += __shfl_xor(a0.x, off, 64); a0.y += __shfl_xor(a0.y, off, 64);
        a0.z += __shfl_xor(a0.z, off, 64); a0.w += __shfl_xor(a0.w, off, 64);
        a1.x += __shfl_xor(a1.x, off, 64); a1.y += __shfl_xor(a1.y, off, 64);
        a1.z += __shfl_xor(a1.z, off, 64); a1.w += __shfl_xor(a1.w, off, 64);
    }

    const float inv = 1.f / (den + 1e-16f);
    if (!FINAL) {
        if (g == 0) {
            float4 v0, v1;
            v0.x = a0.x * inv; v0.x = v0.x > 0.f ? v0.x : expm1f(v0.x);
            v0.y = a0.y * inv; v0.y = v0.y > 0.f ? v0.y : expm1f(v0.y);
            v0.z = a0.z * inv; v0.z = v0.z > 0.f ? v0.z : expm1f(v0.z);
            v0.w = a0.w * inv; v0.w = v0.w > 0.f ? v0.w : expm1f(v0.w);
            v1.x = a1.x * inv; v1.x = v1.x > 0.f ? v1.x : expm1f(v1.x);
            v1.y = a1.y * inv; v1.y = v1.y > 0.f ? v1.y : expm1f(v1.y);
            v1.z = a1.z * inv; v1.z = v1.z > 0.f ? v1.z : expm1f(v1.z);
            v1.w = a1.w * inv; v1.w = v1.w > 0.f ? v1.w : expm1f(v1.w);
            float4* op = (float4*)(outp + (size_t)n * 64 + sl * 8);
            op[0] = v0; op[1] = v1;
        }
    } else {
        const float4* wp = (const float4*)(whead + sl * 8);
        const float4 w0 = wp[0], w1 = wp[1];
        float v = (a0.x * w0.x + a0.y * w0.y + a0.z * w0.z + a0.w * w0.w
                 + a1.x * w1.x + a1.y * w1.y + a1.z * w1.z + a1.w * w1.w) * inv;
        #pragma unroll
        for (int off = 1; off <= 4; off <<= 1) v += __shfl_xor(v, off, 64);
        if (lane == 0) outp[n] = v + bhead[0];
    }
}

extern "C" void kernel_launch(void* const* d_in, const int* in_sizes, int n_in,
                              void* d_out, int out_size, void* d_ws, size_t ws_size,
                              hipStream_t stream) {
    const float* x      = (const float*)d_in[0];
    const int*   eidx   = (const int*)d_in[1];
    const float* ew     = (const float*)d_in[2];
    const float* tim    = (const float*)d_in[3];
    const float* omega0 = (const float*)d_in[4];
    const float* phase0 = (const float*)d_in[5];
    const float* W0     = (const float*)d_in[6];
    const float* asrc0  = (const float*)d_in[7];
    const float* adst0  = (const float*)d_in[8];
    const float* omega1 = (const float*)d_in[9];
    const float* phase1 = (const float*)d_in[10];
    const float* W1     = (const float*)d_in[11];
    const float* asrc1  = (const float*)d_in[12];
    const float* adst1  = (const float*)d_in[13];
    const float* Whead  = (const float*)d_in[14];
    const float* bhead  = (const float*)d_in[15];
    float* out = (float*)d_out;

    const int* src = eidx;
    const int* dst = eidx + N_EDGES;

    float* ws = (float*)d_ws;
    float* hfeat = ws;                               // N*64
    float* x1    = hfeat + (size_t)N_NODES * 64;     // N*64
    float* s_src = x1    + (size_t)N_NODES * 64;     // N*4
    float* s_dst = s_src + (size_t)N_NODES * 4;      // N*4
    int2* epair  = (int2*)(s_dst + (size_t)N_NODES * 4);   // E (8B each)
    int* deg     = (int*)(epair + (size_t)N_EDGES);  // N
    int* rowptr  = deg + N_NODES;                    // N
    int* bsum    = rowptr + N_NODES;                 // 256
    int* rank    = (int*)x1;                         // E ints, aliases x1 (dead until aggregate<0>)

    const int tf_grid   = (N_NODES + 7) / 8;
    const int edge_grid = (N_EDGES + 255) / 256;
    const int agg_grid  = (N_NODES + 3) / 4;
    const int sc_grid   = ((N_EDGES + SC_CHUNK - 1) / SC_CHUNK) * NSEG;

    // ---- CSR build (edge structure shared by both layers) ----
    hipMemsetAsync(deg, 0, N_NODES * sizeof(int), stream);
    hist_kernel<<<edge_grid, 256, 0, stream>>>(dst, deg, rank);
    scanA_kernel<<<NB_SCAN, 256, 0, stream>>>(deg, bsum);
    scanB_kernel<<<1, 256, 0, stream>>>(bsum);
    scanC_kernel<<<NB_SCAN, 256, 0, stream>>>(deg, bsum, rowptr);
    scatter_kernel<<<sc_grid, 256, 0, stream>>>(dst, src, ew, rank, rowptr, epair);

    // ---- layer 0 ----
    transform_kernel<128><<<tf_grid, 512, 0, stream>>>(
        x, tim, omega0, phase0, W0, asrc0, adst0, hfeat, s_src, s_dst);
    aggregate_kernel<0><<<agg_grid, 256, 0, stream>>>(
        rowptr, deg, epair, s_src, s_dst, hfeat, Whead, bhead, x1);

    // ---- layer 1 (+ fused linear head) ----
    transform_kernel<64><<<tf_grid, 512, 0, stream>>>(
        x1, tim, omega1, phase1, W1, asrc1, adst1, hfeat, s_src, s_dst);
    aggregate_kernel<1><<<agg_grid, 256, 0, stream>>>(
        rowptr, deg, epair, s_src, s_dst, hfeat, Whead, bhead, out);
}

// Round 5
// 380.053 us; speedup vs baseline: 3.9055x; 1.0041x over previous
//
#include <hip/hip_runtime.h>
#include <hip/hip_bf16.h>
#include <math.h>

#define N_NODES 50000
#define N_EDGES 1600000
#define TE 64
#define NB_SCAN 196   // ceil(50000/256)
#define LOG2E 1.44269504088896340736f
#define SC_CHUNK 2048
#define NSEG 8        // dst-range segments (one per XCD)
#define SEG_W (N_NODES / NSEG)   // 6250

// ---------------- node transform ----------------
// h = concat(x, cos(t*omega+phase)) @ W ; also s_src[n,h], s_dst[n,h] (pre-scaled by log2e)
template<int IN_DIM>
__global__ __launch_bounds__(512) void transform_kernel(
    const float* __restrict__ xin, const float* __restrict__ tim,
    const float* __restrict__ omega, const float* __restrict__ phase,
    const float* __restrict__ W, const float* __restrict__ asrc,
    const float* __restrict__ adst,
    float* __restrict__ hfeat, float* __restrict__ s_src, float* __restrict__ s_dst)
{
    constexpr int K = IN_DIM + TE;
    constexpr int NPB = 8;              // nodes per block (512 threads / 64 cols)
    __shared__ float a[NPB][K];
    const int tid = threadIdx.x;
    const int base = blockIdx.x * NPB;

    for (int i = tid; i < NPB * K; i += 512) {
        int nl = i / K, k = i - nl * K;
        int n = base + nl;
        if (n < N_NODES) {
            a[nl][k] = (k < IN_DIM) ? xin[(size_t)n * IN_DIM + k]
                                    : cosf(tim[n] * omega[k - IN_DIM] + phase[k - IN_DIM]);
        }
    }
    __syncthreads();

    const int nl = tid >> 6, col = tid & 63;
    const int n = base + nl;
    if (n >= N_NODES) return;

    float acc = 0.f;
    #pragma unroll 4
    for (int k = 0; k < K; ++k) acc += a[nl][k] * W[k * 64 + col];
    hfeat[(size_t)n * 64 + col] = acc;

    float vs = acc * asrc[col];
    float vd = acc * adst[col];
    #pragma unroll
    for (int off = 8; off; off >>= 1) {
        vs += __shfl_xor(vs, off, 64);
        vd += __shfl_xor(vd, off, 64);
    }
    if ((col & 15) == 0) {
        s_src[n * 4 + (col >> 4)] = vs * LOG2E;   // exp2 domain
        s_dst[n * 4 + (col >> 4)] = vd * LOG2E;
    }
}

// ---------------- CSR build ----------------
// deg count + per-edge rank (order within its dst segment)
__global__ __launch_bounds__(256) void hist_kernel(
    const int* __restrict__ dst, int* __restrict__ deg, int* __restrict__ rank)
{
    int e = blockIdx.x * 256 + threadIdx.x;
    if (e < N_EDGES) rank[e] = atomicAdd(deg + dst[e], 1);
}

__global__ __launch_bounds__(256) void scanA_kernel(
    const int* __restrict__ deg, int* __restrict__ bsum)
{
    __shared__ int sd[4];
    int i = blockIdx.x * 256 + threadIdx.x;
    int v = (i < N_NODES) ? deg[i] : 0;
    #pragma unroll
    for (int off = 32; off; off >>= 1) v += __shfl_xor(v, off, 64);
    if ((threadIdx.x & 63) == 0) sd[threadIdx.x >> 6] = v;
    __syncthreads();
    if (threadIdx.x == 0) bsum[blockIdx.x] = sd[0] + sd[1] + sd[2] + sd[3];
}

__global__ __launch_bounds__(256) void scanB_kernel(int* __restrict__ bsum)
{
    __shared__ int s[256];
    int t = threadIdx.x;
    int v = (t < NB_SCAN) ? bsum[t] : 0;
    s[t] = v;
    __syncthreads();
    #pragma unroll
    for (int off = 1; off < 256; off <<= 1) {
        int u = (t >= off) ? s[t - off] : 0;
        __syncthreads();
        s[t] += u;
        __syncthreads();
    }
    if (t < NB_SCAN) bsum[t] = s[t] - v;   // exclusive
}

__global__ __launch_bounds__(256) void scanC_kernel(
    const int* __restrict__ deg, const int* __restrict__ bsum,
    int* __restrict__ rowptr)
{
    __shared__ int s[256];
    int t = threadIdx.x;
    int i = blockIdx.x * 256 + t;
    int v = (i < N_NODES) ? deg[i] : 0;
    s[t] = v;
    __syncthreads();
    #pragma unroll
    for (int off = 1; off < 256; off <<= 1) {
        int u = (t >= off) ? s[t - off] : 0;
        __syncthreads();
        s[t] += u;
        __syncthreads();
    }
    int excl = s[t] - v + bsum[blockIdx.x];
    if (i < N_NODES) rowptr[i] = excl;
}

// XCD-affine scatter: block tag (blockIdx%8) owns one dst-range segment; the
// 1.6MB epair slice per segment stays resident in the owning XCD's L2, so
// random 8B writes merge into full lines before writeback. Atomic-free (rank
// precomputed in hist). Correct for ANY block->XCD mapping; %8 only buys locality.
__global__ __launch_bounds__(256) void scatter_kernel(
    const int* __restrict__ dst, const int* __restrict__ src,
    const float* __restrict__ ew, const int* __restrict__ rank,
    const int* __restrict__ rowptr, int2* __restrict__ epair)
{
    const int seg = blockIdx.x & (NSEG - 1);
    const int lo = seg * SEG_W, hi = lo + SEG_W;
    const int base = (blockIdx.x >> 3) * SC_CHUNK;
    const int end = (base + SC_CHUNK < N_EDGES) ? base + SC_CHUNK : N_EDGES;
    for (int e = base + threadIdx.x; e < end; e += 256) {
        int d = dst[e];
        if (d >= lo && d < hi) {
            epair[rowptr[d] + rank[e]] = make_int2(src[e], __float_as_int(ew[e]));
        }
    }
}

// ---------------- fused per-dst aggregation ----------------
// one wave per node; 8 subgroups x 8 lanes, 8 edges in flight;
// each lane holds 8 features (two float4): cols [sl*8, sl*8+8).
// no max-subtraction (scores O(1), softmax is shift-invariant); exp2 domain.
template<int FINAL>
__global__ __launch_bounds__(256) void aggregate_kernel(
    const int* __restrict__ rowptr, const int* __restrict__ deg,
    const int2* __restrict__ epair,
    const float* __restrict__ s_src, const float* __restrict__ s_dst,
    const float* __restrict__ hfeat,
    const float* __restrict__ whead, const float* __restrict__ bhead,
    float* __restrict__ outp)
{
    const int n = blockIdx.x * 4 + (threadIdx.x >> 6);
    if (n >= N_NODES) return;
    const int lane = threadIdx.x & 63;
    const int g = lane >> 3;          // subgroup (edge slot 0..7)
    const int sl = lane & 7;          // feature octet
    const int hh = sl >> 1;           // head of my features
    const float sdst = s_dst[n * 4 + hh];
    const int beg = rowptr[n];
    const int cnt = deg[n];

    float den = 0.f;
    float4 a0 = make_float4(0.f, 0.f, 0.f, 0.f);
    float4 a1 = make_float4(0.f, 0.f, 0.f, 0.f);

    int i = g;
    int2 ep = (i < cnt) ? epair[beg + i] : make_int2(0, 0);
    while (i < cnt) {
        const int inext = i + 8;
        int2 epn = (inext < cnt) ? epair[beg + inext] : make_int2(0, 0);
        const int s = ep.x;
        const float w = __int_as_float(ep.y);
        float sc = s_src[(size_t)s * 4 + hh] + sdst;
        sc = fmaxf(sc, 0.2f * sc);                       // leaky relu (log2 domain)
        const float p = __builtin_amdgcn_exp2f(sc) * w;
        const float4* hp = (const float4*)(hfeat + (size_t)s * 64 + sl * 8);
        const float4 h0 = hp[0];
        const float4 h1 = hp[1];
        den += p;
        a0.x = fmaf(p, h0.x, a0.x); a0.y = fmaf(p, h0.y, a0.y);
        a0.z = fmaf(p, h0.z, a0.z); a0.w = fmaf(p, h0.w, a0.w);
        a1.x = fmaf(p, h1.x, a1.x); a1.y = fmaf(p, h1.y, a1.y);
        a1.z = fmaf(p, h1.z, a1.z); a1.w = fmaf(p, h1.w, a1.w);
        ep = epn; i = inext;
    }

    // merge 8 subgroups (lane bits 3,4,5)
    #pragma unroll
    for (int off = 8; off <= 32; off <<= 1) {
        den  += __shfl_xor(den, off, 64);
        a0.x += __shfl_xor(a0.x, off, 64); a0.y += __shfl_xor(a0.y, off, 64);
        a0.z += __shfl_xor(a0.z, off, 64); a0.w += __shfl_xor(a0.w, off, 64);
        a1.x += __shfl_xor(a1.x, off, 64); a1.y += __shfl_xor(a1.y, off, 64);
        a1.z += __shfl_xor(a1.z, off, 64); a1.w += __shfl_xor(a1.w, off, 64);
    }

    const float inv = 1.f / (den + 1e-16f);
    if (!FINAL) {
        if (g == 0) {
            float4 v0, v1;
            v0.x = a0.x * inv; v0.x = v0.x > 0.f ? v0.x : expm1f(v0.x);
            v0.y = a0.y * inv; v0.y = v0.y > 0.f ? v0.y : expm1f(v0.y);
            v0.z = a0.z * inv; v0.z = v0.z > 0.f ? v0.z : expm1f(v0.z);
            v0.w = a0.w * inv; v0.w = v0.w > 0.f ? v0.w : expm1f(v0.w);
            v1.x = a1.x * inv; v1.x = v1.x > 0.f ? v1.x : expm1f(v1.x);
            v1.y = a1.y * inv; v1.y = v1.y > 0.f ? v1.y : expm1f(v1.y);
            v1.z = a1.z * inv; v1.z = v1.z > 0.f ? v1.z : expm1f(v1.z);
            v1.w = a1.w * inv; v1.w = v1.w > 0.f ? v1.w : expm1f(v1.w);
            float4* op = (float4*)(outp + (size_t)n * 64 + sl * 8);
            op[0] = v0; op[1] = v1;
        }
    } else {
        const float4* wp = (const float4*)(whead + sl * 8);
        const float4 w0 = wp[0], w1 = wp[1];
        float v = (a0.x * w0.x + a0.y * w0.y + a0.z * w0.z + a0.w * w0.w
                 + a1.x * w1.x + a1.y * w1.y + a1.z * w1.z + a1.w * w1.w) * inv;
        #pragma unroll
        for (int off = 1; off <= 4; off <<= 1) v += __shfl_xor(v, off, 64);
        if (lane == 0) outp[n] = v + bhead[0];
    }
}

extern "C" void kernel_launch(void* const* d_in, const int* in_sizes, int n_in,
                              void* d_out, int out_size, void* d_ws, size_t ws_size,
                              hipStream_t stream) {
    const float* x      = (const float*)d_in[0];
    const int*   eidx   = (const int*)d_in[1];
    const float* ew     = (const float*)d_in[2];
    const float* tim    = (const float*)d_in[3];
    const float* omega0 = (const float*)d_in[4];
    const float* phase0 = (const float*)d_in[5];
    const float* W0     = (const float*)d_in[6];
    const float* asrc0  = (const float*)d_in[7];
    const float* adst0  = (const float*)d_in[8];
    const float* omega1 = (const float*)d_in[9];
    const float* phase1 = (const float*)d_in[10];
    const float* W1     = (const float*)d_in[11];
    const float* asrc1  = (const float*)d_in[12];
    const float* adst1  = (const float*)d_in[13];
    const float* Whead  = (const float*)d_in[14];
    const float* bhead  = (const float*)d_in[15];
    float* out = (float*)d_out;

    const int* src = eidx;
    const int* dst = eidx + N_EDGES;

    float* ws = (float*)d_ws;
    float* hfeat = ws;                               // N*64
    float* x1    = hfeat + (size_t)N_NODES * 64;     // N*64
    float* s_src = x1    + (size_t)N_NODES * 64;     // N*4
    float* s_dst = s_src + (size_t)N_NODES * 4;      // N*4
    int2* epair  = (int2*)(s_dst + (size_t)N_NODES * 4);   // E (8B each)
    int* deg     = (int*)(epair + (size_t)N_EDGES);  // N
    int* rowptr  = deg + N_NODES;                    // N
    int* bsum    = rowptr + N_NODES;                 // 256
    int* rank    = (int*)x1;                         // E ints, aliases x1 (dead until aggregate<0>)

    const int tf_grid   = (N_NODES + 7) / 8;
    const int edge_grid = (N_EDGES + 255) / 256;
    const int agg_grid  = (N_NODES + 3) / 4;
    const int sc_grid   = ((N_EDGES + SC_CHUNK - 1) / SC_CHUNK) * NSEG;

    // ---- CSR build (edge structure shared by both layers) ----
    hipMemsetAsync(deg, 0, N_NODES * sizeof(int), stream);
    hist_kernel<<<edge_grid, 256, 0, stream>>>(dst, deg, rank);
    scanA_kernel<<<NB_SCAN, 256, 0, stream>>>(deg, bsum);
    scanB_kernel<<<1, 256, 0, stream>>>(bsum);
    scanC_kernel<<<NB_SCAN, 256, 0, stream>>>(deg, bsum, rowptr);
    scatter_kernel<<<sc_grid, 256, 0, stream>>>(dst, src, ew, rank, rowptr, epair);

    // ---- layer 0 ----
    transform_kernel<128><<<tf_grid, 512, 0, stream>>>(
        x, tim, omega0, phase0, W0, asrc0, adst0, hfeat, s_src, s_dst);
    aggregate_kernel<0><<<agg_grid, 256, 0, stream>>>(
        rowptr, deg, epair, s_src, s_dst, hfeat, Whead, bhead, x1);

    // ---- layer 1 (+ fused linear head) ----
    transform_kernel<64><<<tf_grid, 512, 0, stream>>>(
        x1, tim, omega1, phase1, W1, asrc1, adst1, hfeat, s_src, s_dst);
    aggregate_kernel<1><<<agg_grid, 256, 0, stream>>>(
        rowptr, deg, epair, s_src, s_dst, hfeat, Whead, bhead, out);
}

// Round 6
// 349.437 us; speedup vs baseline: 4.2477x; 1.0876x over previous
//
#include <hip/hip_runtime.h>
#include <hip/hip_bf16.h>
#include <math.h>

#define N_NODES 50000
#define N_EDGES 1600000
#define TE 64
#define NB_SCAN 196   // ceil(50000/256)
#define LOG2E 1.44269504088896340736f
#define SC_CHUNK 2048
#define NSEG 8        // dst-range segments (one per XCD)
#define SEG_W (N_NODES / NSEG)   // 6250

// ---------------- node transform ----------------
// h = concat(x, cos(t*omega+phase)) @ W ; also s_src[n,h], s_dst[n,h] (pre-scaled by log2e)
// 256 thr = 16 nodes x 16 threads; each thread computes 4 output cols (float4 acc,
// 4 independent FMA chains). W staged in LDS (float4 reads); a padded +1 to
// de-conflict the 4 node-rows per wave.
template<int IN_DIM>
__global__ __launch_bounds__(256) void transform_kernel(
    const float* __restrict__ xin, const float* __restrict__ tim,
    const float* __restrict__ omega, const float* __restrict__ phase,
    const float* __restrict__ W, const float* __restrict__ asrc,
    const float* __restrict__ adst,
    float* __restrict__ hfeat, float* __restrict__ s_src, float* __restrict__ s_dst)
{
    constexpr int K = IN_DIM + TE;
    constexpr int KP = K + 1;           // padded row (bank de-conflict)
    constexpr int NPB = 16;             // nodes per block
    __shared__ float a[NPB * KP];
    __shared__ float w[K * 64];
    const int tid = threadIdx.x;
    const int base = blockIdx.x * NPB;  // grid exact: 50000/16 = 3125

    // stage W: K*64 floats as float4, coalesced
    for (int i = tid; i < K * 16; i += 256)
        ((float4*)w)[i] = ((const float4*)W)[i];

    // stage a = concat(x_row, cos(t*omega+phase))
    for (int i = tid; i < NPB * K; i += 256) {
        int nl = i / K, k = i - nl * K;
        int n = base + nl;
        a[nl * KP + k] = (k < IN_DIM)
            ? xin[(size_t)n * IN_DIM + k]
            : cosf(tim[n] * omega[k - IN_DIM] + phase[k - IN_DIM]);
    }
    __syncthreads();

    const int nl = tid >> 4;        // node within block
    const int sl = tid & 15;        // col slot: cols [sl*4, sl*4+4)
    const int n = base + nl;

    float4 acc = make_float4(0.f, 0.f, 0.f, 0.f);
    const float* arow = a + nl * KP;
    const float* wcol = w + sl * 4;
    #pragma unroll 4
    for (int k = 0; k < K; ++k) {
        const float av = arow[k];
        const float4 w4 = *(const float4*)(wcol + k * 64);
        acc.x = fmaf(av, w4.x, acc.x);
        acc.y = fmaf(av, w4.y, acc.y);
        acc.z = fmaf(av, w4.z, acc.z);
        acc.w = fmaf(av, w4.w, acc.w);
    }

    *(float4*)(hfeat + (size_t)n * 64 + sl * 4) = acc;

    const float4 as = *(const float4*)(asrc + sl * 4);
    const float4 ad = *(const float4*)(adst + sl * 4);
    float vs = acc.x * as.x + acc.y * as.y + acc.z * as.z + acc.w * as.w;
    float vd = acc.x * ad.x + acc.y * ad.y + acc.z * ad.z + acc.w * ad.w;
    vs += __shfl_xor(vs, 1, 64); vs += __shfl_xor(vs, 2, 64);
    vd += __shfl_xor(vd, 1, 64); vd += __shfl_xor(vd, 2, 64);
    if ((sl & 3) == 0) {
        s_src[n * 4 + (sl >> 2)] = vs * LOG2E;   // exp2 domain
        s_dst[n * 4 + (sl >> 2)] = vd * LOG2E;
    }
}

// ---------------- CSR build ----------------
// deg count + per-edge rank (order within its dst segment)
__global__ __launch_bounds__(256) void hist_kernel(
    const int* __restrict__ dst, int* __restrict__ deg, int* __restrict__ rank)
{
    int e = blockIdx.x * 256 + threadIdx.x;
    if (e < N_EDGES) rank[e] = atomicAdd(deg + dst[e], 1);
}

__global__ __launch_bounds__(256) void scanA_kernel(
    const int* __restrict__ deg, int* __restrict__ bsum)
{
    __shared__ int sd[4];
    int i = blockIdx.x * 256 + threadIdx.x;
    int v = (i < N_NODES) ? deg[i] : 0;
    #pragma unroll
    for (int off = 32; off; off >>= 1) v += __shfl_xor(v, off, 64);
    if ((threadIdx.x & 63) == 0) sd[threadIdx.x >> 6] = v;
    __syncthreads();
    if (threadIdx.x == 0) bsum[blockIdx.x] = sd[0] + sd[1] + sd[2] + sd[3];
}

__global__ __launch_bounds__(256) void scanB_kernel(int* __restrict__ bsum)
{
    __shared__ int s[256];
    int t = threadIdx.x;
    int v = (t < NB_SCAN) ? bsum[t] : 0;
    s[t] = v;
    __syncthreads();
    #pragma unroll
    for (int off = 1; off < 256; off <<= 1) {
        int u = (t >= off) ? s[t - off] : 0;
        __syncthreads();
        s[t] += u;
        __syncthreads();
    }
    if (t < NB_SCAN) bsum[t] = s[t] - v;   // exclusive
}

__global__ __launch_bounds__(256) void scanC_kernel(
    const int* __restrict__ deg, const int* __restrict__ bsum,
    int* __restrict__ rowptr)
{
    __shared__ int s[256];
    int t = threadIdx.x;
    int i = blockIdx.x * 256 + t;
    int v = (i < N_NODES) ? deg[i] : 0;
    s[t] = v;
    __syncthreads();
    #pragma unroll
    for (int off = 1; off < 256; off <<= 1) {
        int u = (t >= off) ? s[t - off] : 0;
        __syncthreads();
        s[t] += u;
        __syncthreads();
    }
    int excl = s[t] - v + bsum[blockIdx.x];
    if (i < N_NODES) rowptr[i] = excl;
}

// XCD-affine scatter: block tag (blockIdx%8) owns one dst-range segment; the
// 1.6MB epair slice per segment stays resident in the owning XCD's L2, so
// random 8B writes merge into full lines before writeback. Atomic-free (rank
// precomputed in hist). Correct for ANY block->XCD mapping; %8 only buys locality.
__global__ __launch_bounds__(256) void scatter_kernel(
    const int* __restrict__ dst, const int* __restrict__ src,
    const float* __restrict__ ew, const int* __restrict__ rank,
    const int* __restrict__ rowptr, int2* __restrict__ epair)
{
    const int seg = blockIdx.x & (NSEG - 1);
    const int lo = seg * SEG_W, hi = lo + SEG_W;
    const int base = (blockIdx.x >> 3) * SC_CHUNK;
    const int end = (base + SC_CHUNK < N_EDGES) ? base + SC_CHUNK : N_EDGES;
    for (int e = base + threadIdx.x; e < end; e += 256) {
        int d = dst[e];
        if (d >= lo && d < hi) {
            epair[rowptr[d] + rank[e]] = make_int2(src[e], __float_as_int(ew[e]));
        }
    }
}

// ---------------- fused per-dst aggregation ----------------
// one wave per node; 8 subgroups x 8 lanes, 8 edges in flight;
// each lane holds 8 features (two float4): cols [sl*8, sl*8+8).
// no max-subtraction (scores O(1), softmax is shift-invariant); exp2 domain.
template<int FINAL>
__global__ __launch_bounds__(256) void aggregate_kernel(
    const int* __restrict__ rowptr, const int* __restrict__ deg,
    const int2* __restrict__ epair,
    const float* __restrict__ s_src, const float* __restrict__ s_dst,
    const float* __restrict__ hfeat,
    const float* __restrict__ whead, const float* __restrict__ bhead,
    float* __restrict__ outp)
{
    const int n = blockIdx.x * 4 + (threadIdx.x >> 6);
    if (n >= N_NODES) return;
    const int lane = threadIdx.x & 63;
    const int g = lane >> 3;          // subgroup (edge slot 0..7)
    const int sl = lane & 7;          // feature octet
    const int hh = sl >> 1;           // head of my features
    const float sdst = s_dst[n * 4 + hh];
    const int beg = rowptr[n];
    const int cnt = deg[n];

    float den = 0.f;
    float4 a0 = make_float4(0.f, 0.f, 0.f, 0.f);
    float4 a1 = make_float4(0.f, 0.f, 0.f, 0.f);

    int i = g;
    int2 ep = (i < cnt) ? epair[beg + i] : make_int2(0, 0);
    while (i < cnt) {
        const int inext = i + 8;
        int2 epn = (inext < cnt) ? epair[beg + inext] : make_int2(0, 0);
        const int s = ep.x;
        const float w = __int_as_float(ep.y);
        float sc = s_src[(size_t)s * 4 + hh] + sdst;
        sc = fmaxf(sc, 0.2f * sc);                       // leaky relu (log2 domain)
        const float p = __builtin_amdgcn_exp2f(sc) * w;
        const float4* hp = (const float4*)(hfeat + (size_t)s * 64 + sl * 8);
        const float4 h0 = hp[0];
        const float4 h1 = hp[1];
        den += p;
        a0.x = fmaf(p, h0.x, a0.x); a0.y = fmaf(p, h0.y, a0.y);
        a0.z = fmaf(p, h0.z, a0.z); a0.w = fmaf(p, h0.w, a0.w);
        a1.x = fmaf(p, h1.x, a1.x); a1.y = fmaf(p, h1.y, a1.y);
        a1.z = fmaf(p, h1.z, a1.z); a1.w = fmaf(p, h1.w, a1.w);
        ep = epn; i = inext;
    }

    // merge 8 subgroups (lane bits 3,4,5)
    #pragma unroll
    for (int off = 8; off <= 32; off <<= 1) {
        den  += __shfl_xor(den, off, 64);
        a0.x += __shfl_xor(a0.x, off, 64); a0.y += __shfl_xor(a0.y, off, 64);
        a0.z += __shfl_xor(a0.z, off, 64); a0.w += __shfl_xor(a0.w, off, 64);
        a1.x += __shfl_xor(a1.x, off, 64); a1.y += __shfl_xor(a1.y, off, 64);
        a1.z += __shfl_xor(a1.z, off, 64); a1.w += __shfl_xor(a1.w, off, 64);
    }

    const float inv = 1.f / (den + 1e-16f);
    if (!FINAL) {
        if (g == 0) {
            float4 v0, v1;
            v0.x = a0.x * inv; v0.x = v0.x > 0.f ? v0.x : expm1f(v0.x);
            v0.y = a0.y * inv; v0.y = v0.y > 0.f ? v0.y : expm1f(v0.y);
            v0.z = a0.z * inv; v0.z = v0.z > 0.f ? v0.z : expm1f(v0.z);
            v0.w = a0.w * inv; v0.w = v0.w > 0.f ? v0.w : expm1f(v0.w);
            v1.x = a1.x * inv; v1.x = v1.x > 0.f ? v1.x : expm1f(v1.x);
            v1.y = a1.y * inv; v1.y = v1.y > 0.f ? v1.y : expm1f(v1.y);
            v1.z = a1.z * inv; v1.z = v1.z > 0.f ? v1.z : expm1f(v1.z);
            v1.w = a1.w * inv; v1.w = v1.w > 0.f ? v1.w : expm1f(v1.w);
            float4* op = (float4*)(outp + (size_t)n * 64 + sl * 8);
            op[0] = v0; op[1] = v1;
        }
    } else {
        const float4* wp = (const float4*)(whead + sl * 8);
        const float4 w0 = wp[0], w1 = wp[1];
        float v = (a0.x * w0.x + a0.y * w0.y + a0.z * w0.z + a0.w * w0.w
                 + a1.x * w1.x + a1.y * w1.y + a1.z * w1.z + a1.w * w1.w) * inv;
        #pragma unroll
        for (int off = 1; off <= 4; off <<= 1) v += __shfl_xor(v, off, 64);
        if (lane == 0) outp[n] = v + bhead[0];
    }
}

extern "C" void kernel_launch(void* const* d_in, const int* in_sizes, int n_in,
                              void* d_out, int out_size, void* d_ws, size_t ws_size,
                              hipStream_t stream) {
    const float* x      = (const float*)d_in[0];
    const int*   eidx   = (const int*)d_in[1];
    const float* ew     = (const float*)d_in[2];
    const float* tim    = (const float*)d_in[3];
    const float* omega0 = (const float*)d_in[4];
    const float* phase0 = (const float*)d_in[5];
    const float* W0     = (const float*)d_in[6];
    const float* asrc0  = (const float*)d_in[7];
    const float* adst0  = (const float*)d_in[8];
    const float* omega1 = (const float*)d_in[9];
    const float* phase1 = (const float*)d_in[10];
    const float* W1     = (const float*)d_in[11];
    const float* asrc1  = (const float*)d_in[12];
    const float* adst1  = (const float*)d_in[13];
    const float* Whead  = (const float*)d_in[14];
    const float* bhead  = (const float*)d_in[15];
    float* out = (float*)d_out;

    const int* src = eidx;
    const int* dst = eidx + N_EDGES;

    float* ws = (float*)d_ws;
    float* hfeat = ws;                               // N*64
    float* x1    = hfeat + (size_t)N_NODES * 64;     // N*64
    float* s_src = x1    + (size_t)N_NODES * 64;     // N*4
    float* s_dst = s_src + (size_t)N_NODES * 4;      // N*4
    int2* epair  = (int2*)(s_dst + (size_t)N_NODES * 4);   // E (8B each)
    int* deg     = (int*)(epair + (size_t)N_EDGES);  // N
    int* rowptr  = deg + N_NODES;                    // N
    int* bsum    = rowptr + N_NODES;                 // 256
    int* rank    = (int*)x1;                         // E ints, aliases x1 (dead until aggregate<0>)

    const int tf_grid   = N_NODES / 16;              // 3125, exact
    const int edge_grid = (N_EDGES + 255) / 256;
    const int agg_grid  = (N_NODES + 3) / 4;
    const int sc_grid   = ((N_EDGES + SC_CHUNK - 1) / SC_CHUNK) * NSEG;

    // ---- CSR build (edge structure shared by both layers) ----
    hipMemsetAsync(deg, 0, N_NODES * sizeof(int), stream);
    hist_kernel<<<edge_grid, 256, 0, stream>>>(dst, deg, rank);
    scanA_kernel<<<NB_SCAN, 256, 0, stream>>>(deg, bsum);
    scanB_kernel<<<1, 256, 0, stream>>>(bsum);
    scanC_kernel<<<NB_SCAN, 256, 0, stream>>>(deg, bsum, rowptr);
    scatter_kernel<<<sc_grid, 256, 0, stream>>>(dst, src, ew, rank, rowptr, epair);

    // ---- layer 0 ----
    transform_kernel<128><<<tf_grid, 256, 0, stream>>>(
        x, tim, omega0, phase0, W0, asrc0, adst0, hfeat, s_src, s_dst);
    aggregate_kernel<0><<<agg_grid, 256, 0, stream>>>(
        rowptr, deg, epair, s_src, s_dst, hfeat, Whead, bhead, x1);

    // ---- layer 1 (+ fused linear head) ----
    transform_kernel<64><<<tf_grid, 256, 0, stream>>>(
        x1, tim, omega1, phase1, W1, asrc1, adst1, hfeat, s_src, s_dst);
    aggregate_kernel<1><<<agg_grid, 256, 0, stream>>>(
        rowptr, deg, epair, s_src, s_dst, hfeat, Whead, bhead, out);
}